// Round 10
// baseline (138.783 us; speedup 1.0000x reference)
//
#include <hip/hip_runtime.h>

typedef __attribute__((ext_vector_type(8))) short short8;
typedef __attribute__((ext_vector_type(4))) short short4_t;
typedef __attribute__((ext_vector_type(4))) float f32x4;

#define NEGBIG -1e10f

__device__ __forceinline__ unsigned short f2bf(float x) {
  unsigned int u = __float_as_uint(x);
  u += 0x7FFFu + ((u >> 16) & 1u);          // round-to-nearest-even
  return (unsigned short)(u >> 16);
}
// pack two f32 -> bf16x2 (a low16, b high16), RNE
__device__ __forceinline__ unsigned pack2(float a, float b) {
  unsigned ua = __float_as_uint(a), ub = __float_as_uint(b);
  ua += 0x7FFFu + ((ua >> 16) & 1u);
  ub += 0x7FFFu + ((ub >> 16) & 1u);
  return (ua >> 16) | (ub & 0xFFFF0000u);
}
__device__ __forceinline__ float lo_bf(unsigned p) { return __uint_as_float(p << 16); }
__device__ __forceinline__ float hi_bf(unsigned p) { return __uint_as_float(p & 0xFFFF0000u); }
__device__ __forceinline__ float bfu(unsigned short h) { return __uint_as_float(((unsigned)h) << 16); }

__device__ __forceinline__ float4 mul4(float4 a, float s) {
  float4 r; r.x = a.x*s; r.y = a.y*s; r.z = a.z*s; r.w = a.w*s; return r;
}
__device__ __forceinline__ float4 add4(float4 a, float4 b) {
  float4 r; r.x = a.x+b.x; r.y = a.y+b.y; r.z = a.z+b.z; r.w = a.w+b.w; return r;
}

// ---------------- pool partial: half-panel, asm-pinned streaming ----------
// Grid 4096 = 2048 panels x 2 halves. Block = 4 waves; wave owns 8 tokens.
// Streaming phase: counted-vmcnt pipeline. Batches of 2 tokens = 6
// global_load_dwordx4 issued via inline asm into DISTINCT register quads;
// steady state 12 loads in flight; s_waitcnt vmcnt(6)+sched_barrier between
// batches. The compiler cannot serialize this (R3-R8 all collapsed to
// ~1 load in flight / ~2000cy per load regardless of structure).
__global__ __launch_bounds__(256) void pool_partial(
    const float* __restrict__ left, const float* __restrict__ right,
    const float* __restrict__ femb_l, const float* __restrict__ femb_r,
    unsigned short* __restrict__ partials,   // [4096][768] bf16 (unnormalized)
    float4* __restrict__ meta)               // [4096] (M, S, nz, 0)
{
  int bid   = blockIdx.x;     // 0..4095
  int panel = bid >> 1;       // 0..2047
  int half  = bid & 1;
  int side  = panel >> 10;
  int rem   = panel & 1023;   // b*4 + f
  int f     = rem & 3;
  const float* v    = (side ? right : left) + (size_t)rem * 64 * 768 + (size_t)half * 32 * 768;
  const float* femb = (side ? femb_r : femb_l) + f * 768;

  int tid = threadIdx.x, wave = tid >> 6, lane = tid & 63;

  const float4* fp = (const float4*)femb;
  float4 f0 = fp[lane], f1 = fp[lane + 64], f2 = fp[lane + 128];

  // quiesce all compiler-issued loads so vmcnt counting below is exact
  asm volatile("s_waitcnt vmcnt(0)" ::: "memory");
  __builtin_amdgcn_sched_barrier(0);

  const float* vw = v + (size_t)wave * 8 * 768;   // this wave's 8 tokens

  float4 xa[6], xb[6];
  float d[8];
  unsigned pk[8][6];
  unsigned nzmask = 0;

  // issue 3 loads (one token) from base _p: offsets 0 / 1024B / 2048B
  #define ISSUE_TOK(a0_, a1_, a2_, p_)                                        \
    asm volatile("global_load_dwordx4 %0, %3, off\n\t"                        \
                 "global_load_dwordx4 %1, %3, off offset:1024\n\t"            \
                 "global_load_dwordx4 %2, %3, off offset:2048"                \
                 : "=&v"(a0_), "=&v"(a1_), "=&v"(a2_) : "v"(p_))

  #define ISSUE_BATCH(arr, tok0)                                              \
    { const float* _pA = vw + (tok0) * 768 + lane * 4;                        \
      const float* _pB = _pA + 768;                                           \
      ISSUE_TOK(arr[0], arr[1], arr[2], _pA);                                 \
      ISSUE_TOK(arr[3], arr[4], arr[5], _pB); }

  #define WAITN(n)                                                            \
    asm volatile("s_waitcnt vmcnt(" #n ")" ::: "memory");                     \
    __builtin_amdgcn_sched_barrier(0);

  #define CONSUME_TOK(t, y0, y1, y2)                                          \
    { d[t] = y0.x*f0.x + y0.y*f0.y + y0.z*f0.z + y0.w*f0.w                    \
           + y1.x*f1.x + y1.y*f1.y + y1.z*f1.z + y1.w*f1.w                    \
           + y2.x*f2.x + y2.y*f2.y + y2.z*f2.z + y2.w*f2.w;                   \
      unsigned nzb = __float_as_uint(y0.x) | __float_as_uint(y0.y)            \
                   | __float_as_uint(y0.z) | __float_as_uint(y0.w)            \
                   | __float_as_uint(y1.x) | __float_as_uint(y1.y)            \
                   | __float_as_uint(y1.z) | __float_as_uint(y1.w)            \
                   | __float_as_uint(y2.x) | __float_as_uint(y2.y)            \
                   | __float_as_uint(y2.z) | __float_as_uint(y2.w);           \
      nzmask |= (nzb != 0u) ? (1u << (t)) : 0u;                               \
      pk[t][0] = pack2(y0.x, y0.y); pk[t][1] = pack2(y0.z, y0.w);             \
      pk[t][2] = pack2(y1.x, y1.y); pk[t][3] = pack2(y1.z, y1.w);             \
      pk[t][4] = pack2(y2.x, y2.y); pk[t][5] = pack2(y2.z, y2.w); }

  ISSUE_BATCH(xa, 0);                                  // t0,t1 in flight (6)
  ISSUE_BATCH(xb, 2);                                  // +t2,t3 (12)
  WAITN(6);                                            // t0,t1 ready
  CONSUME_TOK(0, xa[0], xa[1], xa[2]);
  CONSUME_TOK(1, xa[3], xa[4], xa[5]);
  ISSUE_BATCH(xa, 4);                                  // +t4,t5 (12)
  WAITN(6);                                            // t2,t3 ready
  CONSUME_TOK(2, xb[0], xb[1], xb[2]);
  CONSUME_TOK(3, xb[3], xb[4], xb[5]);
  ISSUE_BATCH(xb, 6);                                  // +t6,t7 (12)
  WAITN(6);                                            // t4,t5 ready
  CONSUME_TOK(4, xa[0], xa[1], xa[2]);
  CONSUME_TOK(5, xa[3], xa[4], xa[5]);
  WAITN(0);                                            // t6,t7 ready
  CONSUME_TOK(6, xb[0], xb[1], xb[2]);
  CONSUME_TOK(7, xb[3], xb[4], xb[5]);

  // ---- pipelined cross-lane reductions (8 chains + nz) ----
  #pragma unroll
  for (int sh = 32; sh > 0; sh >>= 1) {
    d[0] += __shfl_xor(d[0], sh);
    d[1] += __shfl_xor(d[1], sh);
    d[2] += __shfl_xor(d[2], sh);
    d[3] += __shfl_xor(d[3], sh);
    d[4] += __shfl_xor(d[4], sh);
    d[5] += __shfl_xor(d[5], sh);
    d[6] += __shfl_xor(d[6], sh);
    d[7] += __shfl_xor(d[7], sh);
    nzmask |= __shfl_xor(nzmask, sh);
  }

  // ---- wave-local softmax pieces over 8 tokens ----
  float l[8], e[8];
  #pragma unroll
  for (int t = 0; t < 8; ++t)
    l[t] = d[t] + (((nzmask >> t) & 1u) ? 0.f : NEGBIG);
  float m01 = fmaxf(l[0], l[1]), m23 = fmaxf(l[2], l[3]);
  float m45 = fmaxf(l[4], l[5]), m67 = fmaxf(l[6], l[7]);
  float m_w = fmaxf(fmaxf(m01, m23), fmaxf(m45, m67));
  #pragma unroll
  for (int t = 0; t < 8; ++t) e[t] = __expf(l[t] - m_w);
  float s_w = ((e[0]+e[1]) + (e[2]+e[3])) + ((e[4]+e[5]) + (e[6]+e[7]));

  __shared__ float m_lds[4], s_lds[4];
  __shared__ int   nz_lds[4];
  __shared__ float acc_lds[4 * 768];   // 12 KB

  if (lane == 0) { m_lds[wave] = m_w; s_lds[wave] = s_w; nz_lds[wave] = (nzmask != 0u); }

  // ---- accumulate from packed registers ----
  float4 A0 = {0,0,0,0}, A1 = {0,0,0,0}, A2 = {0,0,0,0};
  #pragma unroll
  for (int t = 0; t < 8; ++t) {
    float c = e[t];
    A0.x += c * lo_bf(pk[t][0]); A0.y += c * hi_bf(pk[t][0]);
    A0.z += c * lo_bf(pk[t][1]); A0.w += c * hi_bf(pk[t][1]);
    A1.x += c * lo_bf(pk[t][2]); A1.y += c * hi_bf(pk[t][2]);
    A1.z += c * lo_bf(pk[t][3]); A1.w += c * hi_bf(pk[t][3]);
    A2.x += c * lo_bf(pk[t][4]); A2.y += c * hi_bf(pk[t][4]);
    A2.z += c * lo_bf(pk[t][5]); A2.w += c * hi_bf(pk[t][5]);
  }

  __syncthreads();
  float M = fmaxf(fmaxf(m_lds[0], m_lds[1]), fmaxf(m_lds[2], m_lds[3]));
  float S = s_lds[0] * __expf(m_lds[0] - M) + s_lds[1] * __expf(m_lds[1] - M)
          + s_lds[2] * __expf(m_lds[2] - M) + s_lds[3] * __expf(m_lds[3] - M);
  float scale = __expf(m_w - M);   // unnormalized; S goes in meta

  float4* al = (float4*)acc_lds;
  al[wave * 192 +       lane] = mul4(A0, scale);
  al[wave * 192 +  64 + lane] = mul4(A1, scale);
  al[wave * 192 + 128 + lane] = mul4(A2, scale);
  __syncthreads();

  if (tid < 192) {
    float4 A = add4(add4(al[tid], al[192 + tid]),
                    add4(al[384 + tid], al[576 + tid]));
    ushort4 o;
    o.x = f2bf(A.x); o.y = f2bf(A.y); o.z = f2bf(A.z); o.w = f2bf(A.w);
    ((ushort4*)(partials + (size_t)bid * 768))[tid] = o;
  }
  if (tid == 192) {
    int has = nz_lds[0] | nz_lds[1] | nz_lds[2] | nz_lds[3];
    float4 mt; mt.x = M; mt.y = S; mt.z = has ? 1.f : 0.f; mt.w = 0.f;
    meta[bid] = mt;
  }
}

// ---------------- pool merge: combine 2 half-panels -> bf16 concat --------
__global__ __launch_bounds__(192) void pool_merge(
    const unsigned short* __restrict__ partials, const float4* __restrict__ meta,
    const float* __restrict__ empty_attr,
    unsigned short* __restrict__ concat)   // [B, 8, 768] bf16
{
  int panel = blockIdx.x;     // 0..2047
  int tid = threadIdx.x;      // 0..191
  int side = panel >> 10;
  int rem  = panel & 1023;
  int f    = rem & 3;
  int b    = rem >> 2;

  float4 mt0 = meta[panel * 2], mt1 = meta[panel * 2 + 1];
  float M = fmaxf(mt0.x, mt1.x);
  float sc0 = __expf(mt0.x - M), sc1 = __expf(mt1.x - M);
  float S = mt0.y * sc0 + mt1.y * sc1;
  int has = (mt0.z + mt1.z) != 0.f;

  ushort4 q0 = ((const ushort4*)(partials + (size_t)(panel * 2 + 0) * 768))[tid];
  ushort4 q1 = ((const ushort4*)(partials + (size_t)(panel * 2 + 1) * 768))[tid];

  float4 r;
  if (has) {
    float i0 = sc0 / S, i1 = sc1 / S;
    r.x = bfu(q0.x)*i0 + bfu(q1.x)*i1;
    r.y = bfu(q0.y)*i0 + bfu(q1.y)*i1;
    r.z = bfu(q0.z)*i0 + bfu(q1.z)*i1;
    r.w = bfu(q0.w)*i0 + bfu(q1.w)*i1;
  } else {
    r = ((const float4*)empty_attr)[tid];
  }
  ushort4 o;
  o.x = f2bf(r.x); o.y = f2bf(r.y); o.z = f2bf(r.z); o.w = f2bf(r.w);
  size_t base = ((size_t)b * 8 + side * 4 + f) * 192;
  ((ushort4*)concat)[base + tid] = o;
}

// ---------------- GEMM1 split-K ----------------
// A [256,6144] bf16 (K-contig). W1 [1600,6144] f32 (K-contig).
// Grid (100 col-tiles, 8 K-chunks). Each block stages its EXCLUSIVE
// 16col x 768K W1 tile in LDS (bf16) -> W1 read once total.
__global__ __launch_bounds__(256) void gemm1_kernel(
    const unsigned short* __restrict__ A,
    const float* __restrict__ W1,
    float* __restrict__ Hpart)
{
  const int K = 6144, N = 1600, KC = 768;
  int colb = blockIdx.x;          // 0..99
  int kc   = blockIdx.y;          // 0..7
  int col0 = colb * 16;
  int tid = threadIdx.x, wave = tid >> 6, lane = tid & 63;

  __shared__ short wlds[96 * 16 * 8];

  const float* wsrc = W1 + (size_t)col0 * K + kc * KC;
  #pragma unroll
  for (int i = 0; i < 12; ++i) {
    int flat4 = tid + 256 * i;
    int col = flat4 / 192;
    int k   = (flat4 % 192) * 4;
    float4 w = *(const float4*)(wsrc + (size_t)col * K + k);
    short4_t o;
    o[0] = (short)f2bf(w.x); o[1] = (short)f2bf(w.y);
    o[2] = (short)f2bf(w.z); o[3] = (short)f2bf(w.w);
    *(short4_t*)(wlds + (k >> 3) * 128 + col * 8 + (k & 7)) = o;
  }
  __syncthreads();

  int lr = lane & 15;
  const short* a0 = (const short*)A + (size_t)(wave * 64 + lr) * K + kc * KC + (lane >> 4) * 8;
  const short* bptr = wlds + (lane >> 4) * 128 + lr * 8;

  f32x4 acc0 = {}, acc1 = {}, acc2 = {}, acc3 = {};

  #pragma unroll 4
  for (int ks = 0; ks < 24; ++ks) {
    short8 bf  = *(const short8*)(bptr + ks * 512);
    short8 af0 = *(const short8*)(a0 + ks * 32);
    short8 af1 = *(const short8*)(a0 + ks * 32 + 16 * K);
    short8 af2 = *(const short8*)(a0 + ks * 32 + 32 * K);
    short8 af3 = *(const short8*)(a0 + ks * 32 + 48 * K);
    acc0 = __builtin_amdgcn_mfma_f32_16x16x32_bf16(af0, bf, acc0, 0, 0, 0);
    acc1 = __builtin_amdgcn_mfma_f32_16x16x32_bf16(af1, bf, acc1, 0, 0, 0);
    acc2 = __builtin_amdgcn_mfma_f32_16x16x32_bf16(af2, bf, acc2, 0, 0, 0);
    acc3 = __builtin_amdgcn_mfma_f32_16x16x32_bf16(af3, bf, acc3, 0, 0, 0);
  }

  int ccol = lane & 15;
  int crow = (lane >> 4) * 4;
  float* hp = Hpart + (size_t)kc * 256 * N + (size_t)col0 + ccol;
  f32x4 accs[4] = {acc0, acc1, acc2, acc3};
  #pragma unroll
  for (int i = 0; i < 4; ++i) {
    int r = wave * 64 + i * 16 + crow;
    #pragma unroll
    for (int q = 0; q < 4; ++q)
      hp[(size_t)(r + q) * N] = accs[i][q];
  }
}

// ---------------- epilogue: reduce split-K + bias + relu + head GEMM -------
__global__ __launch_bounds__(256) void epilogue_kernel(
    const float* __restrict__ Hpart, const float* __restrict__ b1,
    const float* __restrict__ W2, const float* __restrict__ b2,
    float* __restrict__ out)
{
  const int N = 1600;
  int b = blockIdx.x, tid = threadIdx.x;
  int wave = tid >> 6, lane = tid & 63;
  float s0 = 0.f, s1 = 0.f;
  for (int c = tid; c < N; c += 256) {
    float acc = 0.f;
    #pragma unroll
    for (int kc = 0; kc < 8; ++kc)
      acc += Hpart[((size_t)kc * 256 + b) * N + c];
    float h = fmaxf(acc + b1[c], 0.f);
    s0 += h * W2[c];
    s1 += h * W2[N + c];
  }
  #pragma unroll
  for (int s = 32; s > 0; s >>= 1) {
    s0 += __shfl_xor(s0, s);
    s1 += __shfl_xor(s1, s);
  }
  __shared__ float r0[4], r1[4];
  if (lane == 0) { r0[wave] = s0; r1[wave] = s1; }
  __syncthreads();
  if (tid == 0) {
    out[b * 2 + 0] = r0[0] + r0[1] + r0[2] + r0[3] + b2[0];
    out[b * 2 + 1] = r1[0] + r1[1] + r1[2] + r1[3] + b2[1];
  }
}

extern "C" void kernel_launch(void* const* d_in, const int* in_sizes, int n_in,
                              void* d_out, int out_size, void* d_ws, size_t ws_size,
                              hipStream_t stream) {
  const float* left       = (const float*)d_in[0];
  const float* right      = (const float*)d_in[1];
  const float* femb_l     = (const float*)d_in[2];
  const float* femb_r     = (const float*)d_in[3];
  const float* empty_attr = (const float*)d_in[4];
  const float* W1         = (const float*)d_in[5];
  const float* b1         = (const float*)d_in[6];
  const float* W2         = (const float*)d_in[7];
  const float* b2         = (const float*)d_in[8];
  float* out = (float*)d_out;

  char* ws = (char*)d_ws;
  unsigned short* concat = (unsigned short*)ws;               // [0, 3.15MB)
  float*          Hpart  = (float*)(ws + 3145728);            // [3.15MB, 16.25MB) 8*256*1600*4
  // partials/meta ALIAS Hpart's region (consumed by pool_merge before
  // gemm1 writes Hpart; stream-serial so no hazard):
  unsigned short* partials = (unsigned short*)Hpart;           // 4096*768*2 = 6,291,456 B
  float4*         meta     = (float4*)(ws + 3145728 + 6291456); // 4096*16 = 65,536 B

  hipLaunchKernelGGL(pool_partial, dim3(4096), dim3(256), 0, stream,
                     left, right, femb_l, femb_r, partials, meta);
  hipLaunchKernelGGL(pool_merge, dim3(2048), dim3(192), 0, stream,
                     partials, meta, empty_attr, concat);
  hipLaunchKernelGGL(gemm1_kernel, dim3(100, 8), dim3(256), 0, stream,
                     concat, W1, Hpart);
  hipLaunchKernelGGL(epilogue_kernel, dim3(256), dim3(256), 0, stream,
                     Hpart, b1, W2, b2, out);
}